// Round 1
// baseline (796.083 us; speedup 1.0000x reference)
//
#include <hip/hip_runtime.h>

typedef unsigned short u16;
typedef __bf16 bf16x8 __attribute__((ext_vector_type(8)));
typedef float f32x4 __attribute__((ext_vector_type(4)));

static __device__ __forceinline__ u16 f2bf(float f) {
  unsigned u = __builtin_bit_cast(unsigned, f);
  u = u + 0x7FFFu + ((u >> 16) & 1u);   // RNE
  return (u16)(u >> 16);
}
static __device__ __forceinline__ float bf2f(u16 h) {
  return __builtin_bit_cast(float, (unsigned)h << 16);
}

#define GLOAD_LDS16(g, l) __builtin_amdgcn_global_load_lds(              \
    (const __attribute__((address_space(1))) void*)(g),                  \
    (__attribute__((address_space(3))) void*)(l), 16, 0, 0)

// ---------------- elementwise f32 -> bf16 (4 elems/thread) ----------------
__global__ __launch_bounds__(256) void cvt_f32_bf16(const float* __restrict__ in,
                                                    u16* __restrict__ out, long n4) {
  long i = (long)blockIdx.x * 256 + threadIdx.x;
  if (i >= n4) return;
  float4 v = reinterpret_cast<const float4*>(in)[i];
  ushort4 o;
  o.x = f2bf(v.x); o.y = f2bf(v.y); o.z = f2bf(v.z); o.w = f2bf(v.w);
  reinterpret_cast<ushort4*>(out)[i] = o;
}

// ------------- transpose + convert: W[K][N] f32 -> Wt[N][K] bf16 ----------
__global__ __launch_bounds__(256) void transpose_cvt(const float* __restrict__ W,
                                                     u16* __restrict__ Wt,
                                                     int K, int N) {
  __shared__ float tile[32][33];
  const int tx = threadIdx.x & 31, ty = threadIdx.x >> 5;  // ty: 0..7
  const int n0 = blockIdx.x * 32, k0 = blockIdx.y * 32;
#pragma unroll
  for (int i = 0; i < 4; ++i)
    tile[ty + i * 8][tx] = W[(long)(k0 + ty + i * 8) * N + n0 + tx];
  __syncthreads();
#pragma unroll
  for (int i = 0; i < 4; ++i) {
    int r = ty + i * 8;
    Wt[(long)(n0 + r) * K + k0 + tx] = f2bf(tile[tx][r]);
  }
}

// -------- y [16][77][768] f32 -> yp [16][80][768] bf16, pad rows = 0 -------
__global__ __launch_bounds__(256) void cvt_y_pad(const float* __restrict__ y,
                                                 u16* __restrict__ yp) {
  int idx = blockIdx.x * 256 + threadIdx.x;
  int e = idx * 4;  // element index into [16][80][768]
  int c = e % 768;
  int rb = e / 768;
  int r = rb % 80, b = rb / 80;
  ushort4 o;
  if (r < 77) {
    float4 v = *reinterpret_cast<const float4*>(y + ((long)(b * 77 + r) * 768 + c));
    o.x = f2bf(v.x); o.y = f2bf(v.y); o.z = f2bf(v.z); o.w = f2bf(v.w);
  } else {
    o.x = 0; o.y = 0; o.z = 0; o.w = 0;
  }
  *reinterpret_cast<ushort4*>(yp + e) = o;
}

// ---------------- m97-style 128x128 bf16 GEMM, C = A @ Bt^T + bias --------
// A [M][K] bf16 row-major, Bt [N][K] bf16 row-major, bias [N] f32.
// M % 128 == 0, N % 128 == 0, K % 64 == 0.
template <bool OUT_BF16>
__global__ __launch_bounds__(256) void gemm_bt(const u16* __restrict__ A,
                                               const u16* __restrict__ Bt,
                                               const float* __restrict__ bias,
                                               void* __restrict__ Cv,
                                               int M, int N, int K) {
  __shared__ __align__(16) u16 As[128 * 64];
  __shared__ __align__(16) u16 Bs[128 * 64];
  const int tid = threadIdx.x;
  const int lane = tid & 63, wave = tid >> 6;
  const int lr = lane & 15, lk = lane >> 4;
  const int wr = wave >> 1, wc = wave & 1;
  const long m0 = (long)blockIdx.y * 128, n0 = (long)blockIdx.x * 128;
  f32x4 acc[4][4] = {};

  for (int k0 = 0; k0 < K; k0 += 64) {
#pragma unroll
    for (int it = 0; it < 4; ++it) {
      int c = tid + it * 256;
      int row = c >> 3, colc = c & 7;
      GLOAD_LDS16(A + (m0 + row) * K + k0 + colc * 8, As + c * 8);
      GLOAD_LDS16(Bt + (n0 + row) * K + k0 + colc * 8, Bs + c * 8);
    }
    __syncthreads();
#pragma unroll
    for (int kk = 0; kk < 2; ++kk) {
      bf16x8 af[4], bfr[4];
#pragma unroll
      for (int m = 0; m < 4; ++m)
        af[m] = *reinterpret_cast<const bf16x8*>(As + (wr * 64 + m * 16 + lr) * 64 + kk * 32 + lk * 8);
#pragma unroll
      for (int n = 0; n < 4; ++n)
        bfr[n] = *reinterpret_cast<const bf16x8*>(Bs + (wc * 64 + n * 16 + lr) * 64 + kk * 32 + lk * 8);
#pragma unroll
      for (int m = 0; m < 4; ++m)
#pragma unroll
        for (int n = 0; n < 4; ++n)
          acc[m][n] = __builtin_amdgcn_mfma_f32_16x16x32_bf16(af[m], bfr[n], acc[m][n], 0, 0, 0);
    }
    __syncthreads();
  }

#pragma unroll
  for (int n = 0; n < 4; ++n) {
    long col = n0 + wc * 64 + n * 16 + lr;
    float bb = bias[col];
#pragma unroll
    for (int m = 0; m < 4; ++m) {
#pragma unroll
      for (int j = 0; j < 4; ++j) {
        long row = m0 + wr * 64 + m * 16 + lk * 4 + j;
        float v = acc[m][n][j] + bb;
        if (OUT_BF16)
          ((u16*)Cv)[row * N + col] = f2bf(v);
        else
          ((float*)Cv)[row * N + col] = v;
      }
    }
  }
}

// ---------------- fused attention: 16 q-rows per block, in-place on Q ------
// Q [16*4096][1024] bf16 (overwritten with attention output)
// Kp/Vp [16][80][1024] bf16 (rows 77..79 are padding; masked in softmax)
__global__ __launch_bounds__(256) void attn_fused(u16* __restrict__ Q,
                                                  const u16* __restrict__ Kp,
                                                  const u16* __restrict__ Vp) {
  const int blk = blockIdx.x;
  const int b = blk >> 8;               // 256 blocks per batch (4096/16)
  const int q0 = (blk & 255) << 4;
  const long qoff = ((long)b * 4096 + q0) * 1024;
  const int tid = threadIdx.x;
  const int lane = tid & 63, wave = tid >> 6;
  const int lr = lane & 15, lk = lane >> 4;

  __shared__ float S4[4][16][80];
  __shared__ __align__(16) float Pt[80][16];

  // Phase 1: scores via MFMA; wave w covers k = w*256 .. w*256+255
  f32x4 acc[5] = {};
  const u16* qb = Q + qoff;
  const u16* kb = Kp + (long)b * 80 * 1024;
#pragma unroll
  for (int t = 0; t < 8; ++t) {
    int kk = wave * 8 + t;
    bf16x8 qa = *reinterpret_cast<const bf16x8*>(qb + lr * 1024 + kk * 32 + lk * 8);
#pragma unroll
    for (int n = 0; n < 5; ++n) {
      bf16x8 kf = *reinterpret_cast<const bf16x8*>(kb + (n * 16 + lr) * 1024 + kk * 32 + lk * 8);
      acc[n] = __builtin_amdgcn_mfma_f32_16x16x32_bf16(qa, kf, acc[n], 0, 0, 0);
    }
  }
#pragma unroll
  for (int n = 0; n < 5; ++n)
#pragma unroll
    for (int j = 0; j < 4; ++j)
      S4[wave][lk * 4 + j][n * 16 + lr] = acc[n][j];
  __syncthreads();

  // Phase 2: cross-wave reduce + softmax (row r handled by 16 threads)
  {
    const int r = tid >> 4, ci = tid & 15;
    const float scale = 0.088388347648318447f;  // 1/sqrt(128)
    float v[5];
    float mx = -3e38f;
#pragma unroll
    for (int i = 0; i < 5; ++i) {
      int c = ci + 16 * i;
      float s = (S4[0][r][c] + S4[1][r][c]) + (S4[2][r][c] + S4[3][r][c]);
      s *= scale;
      if (c >= 77) s = -3e38f;
      v[i] = s;
      mx = fmaxf(mx, s);
    }
#pragma unroll
    for (int off = 1; off < 16; off <<= 1) mx = fmaxf(mx, __shfl_xor(mx, off, 64));
    float sum = 0.f, e[5];
#pragma unroll
    for (int i = 0; i < 5; ++i) { e[i] = __expf(v[i] - mx); sum += e[i]; }
#pragma unroll
    for (int off = 1; off < 16; off <<= 1) sum += __shfl_xor(sum, off, 64);
    float inv = 1.f / sum;
#pragma unroll
    for (int i = 0; i < 5; ++i) Pt[ci + 16 * i][r] = e[i] * inv;  // transposed
  }
  __syncthreads();

  // Phase 3: PV (vector f32). Each thread: 4 e-cols x 16 q-rows.
  float oacc[16][4] = {};
  const u16* vb = Vp + (long)b * 80 * 1024 + tid * 4;
  for (int k = 0; k < 80; ++k) {
    ushort4 vv = *reinterpret_cast<const ushort4*>(vb + k * 1024);
    float vf0 = bf2f(vv.x), vf1 = bf2f(vv.y), vf2 = bf2f(vv.z), vf3 = bf2f(vv.w);
    f32x4 pp[4];
    pp[0] = *reinterpret_cast<const f32x4*>(&Pt[k][0]);
    pp[1] = *reinterpret_cast<const f32x4*>(&Pt[k][4]);
    pp[2] = *reinterpret_cast<const f32x4*>(&Pt[k][8]);
    pp[3] = *reinterpret_cast<const f32x4*>(&Pt[k][12]);
#pragma unroll
    for (int q = 0; q < 16; ++q) {
      float pq = pp[q >> 2][q & 3];
      oacc[q][0] += pq * vf0;
      oacc[q][1] += pq * vf1;
      oacc[q][2] += pq * vf2;
      oacc[q][3] += pq * vf3;
    }
  }
  u16* ob = Q + qoff + tid * 4;
#pragma unroll
  for (int q = 0; q < 16; ++q) {
    ushort4 o;
    o.x = f2bf(oacc[q][0]); o.y = f2bf(oacc[q][1]);
    o.z = f2bf(oacc[q][2]); o.w = f2bf(oacc[q][3]);
    *reinterpret_cast<ushort4*>(ob + q * 1024) = o;
  }
}

extern "C" void kernel_launch(void* const* d_in, const int* in_sizes, int n_in,
                              void* d_out, int out_size, void* d_ws, size_t ws_size,
                              hipStream_t stream) {
  const float* x  = (const float*)d_in[0];
  const float* y  = (const float*)d_in[1];
  const float* Wq = (const float*)d_in[2];
  const float* bq = (const float*)d_in[3];
  const float* Wk = (const float*)d_in[4];
  const float* bk = (const float*)d_in[5];
  const float* Wv = (const float*)d_in[6];
  const float* bv = (const float*)d_in[7];
  const float* Wo = (const float*)d_in[8];
  const float* bo = (const float*)d_in[9];

  const int B = 16, Lq = 4096, D = 1024, Dc = 768, Lp = 80;
  const long Mq = (long)B * Lq;  // 65536

  char* p = (char*)d_ws;
  u16* Qb  = (u16*)p; p += (size_t)Mq * D * 2;      // 134 MB: Q, then attn out (in-place)
  u16* Wqt = (u16*)p; p += (size_t)D * D * 2;
  u16* Wkt = (u16*)p; p += (size_t)D * Dc * 2;      // [1024][768]
  u16* Wvt = (u16*)p; p += (size_t)D * Dc * 2;
  u16* Wot = (u16*)p; p += (size_t)D * D * 2;
  u16* yp  = (u16*)p; p += (size_t)B * Lp * Dc * 2; // [16][80][768], pad zeroed
  u16* Kp  = (u16*)p; p += (size_t)B * Lp * D * 2;  // [16][80][1024]
  u16* Vp  = (u16*)p; p += (size_t)B * Lp * D * 2;
  u16* xb  = (u16*)d_out;  // scratch: x as bf16 lives in d_out until final GEMM

  // conversions
  cvt_f32_bf16<<<(int)(Mq * D / 1024), 256, 0, stream>>>(x, xb, Mq * D / 4);
  transpose_cvt<<<dim3(D / 32, D / 32), 256, 0, stream>>>(Wq, Wqt, D, D);
  transpose_cvt<<<dim3(D / 32, Dc / 32), 256, 0, stream>>>(Wk, Wkt, Dc, D);
  transpose_cvt<<<dim3(D / 32, Dc / 32), 256, 0, stream>>>(Wv, Wvt, Dc, D);
  transpose_cvt<<<dim3(D / 32, D / 32), 256, 0, stream>>>(Wo, Wot, D, D);
  cvt_y_pad<<<(B * Lp * Dc / 4) / 256, 256, 0, stream>>>(y, yp);

  // K/V projections: [1280][768] @ [768][1024] -> [1280][1024]
  gemm_bt<true><<<dim3(D / 128, (B * Lp) / 128), 256, 0, stream>>>(yp, Wkt, bk, Kp, B * Lp, D, Dc);
  gemm_bt<true><<<dim3(D / 128, (B * Lp) / 128), 256, 0, stream>>>(yp, Wvt, bv, Vp, B * Lp, D, Dc);

  // Q projection: [65536][1024] @ [1024][1024] -> [65536][1024]
  gemm_bt<true><<<dim3(D / 128, (int)(Mq / 128)), 256, 0, stream>>>(xb, Wqt, bq, Qb, (int)Mq, D, D);

  // fused attention, writes back into Qb
  attn_fused<<<(int)(Mq / 16), 256, 0, stream>>>(Qb, Kp, Vp);

  // output projection: [65536][1024] @ [1024][1024] -> d_out f32
  gemm_bt<false><<<dim3(D / 128, (int)(Mq / 128)), 256, 0, stream>>>(Qb, Wot, bo, d_out, (int)Mq, D, D);
}

// Round 2
// 755.606 us; speedup vs baseline: 1.0536x; 1.0536x over previous
//
#include <hip/hip_runtime.h>

typedef unsigned short u16;
typedef __bf16 bf16x8 __attribute__((ext_vector_type(8)));
typedef float f32x4 __attribute__((ext_vector_type(4)));

static __device__ __forceinline__ u16 f2bf(float f) {
  unsigned u = __builtin_bit_cast(unsigned, f);
  u = u + 0x7FFFu + ((u >> 16) & 1u);   // RNE
  return (u16)(u >> 16);
}
static __device__ __forceinline__ float bf2f(u16 h) {
  return __builtin_bit_cast(float, (unsigned)h << 16);
}

#define GLOAD_LDS16(g, l) __builtin_amdgcn_global_load_lds(              \
    (const __attribute__((address_space(1))) void*)(g),                  \
    (__attribute__((address_space(3))) void*)(l), 16, 0, 0)
#define BAR() asm volatile("s_barrier" ::: "memory")
#define VMCNT(n) asm volatile("s_waitcnt vmcnt(" #n ")" ::: "memory")

// ---------------- elementwise f32 -> bf16 (4 elems/thread) ----------------
__global__ __launch_bounds__(256) void cvt_f32_bf16(const float* __restrict__ in,
                                                    u16* __restrict__ out, long n4) {
  long i = (long)blockIdx.x * 256 + threadIdx.x;
  if (i >= n4) return;
  float4 v = reinterpret_cast<const float4*>(in)[i];
  ushort4 o;
  o.x = f2bf(v.x); o.y = f2bf(v.y); o.z = f2bf(v.z); o.w = f2bf(v.w);
  reinterpret_cast<ushort4*>(out)[i] = o;
}

// ------------- transpose + convert: W[K][N] f32 -> Wt[N][K] bf16 ----------
__global__ __launch_bounds__(256) void transpose_cvt(const float* __restrict__ W,
                                                     u16* __restrict__ Wt,
                                                     int K, int N) {
  __shared__ float tile[32][33];
  const int tx = threadIdx.x & 31, ty = threadIdx.x >> 5;  // ty: 0..7
  const int n0 = blockIdx.x * 32, k0 = blockIdx.y * 32;
#pragma unroll
  for (int i = 0; i < 4; ++i)
    tile[ty + i * 8][tx] = W[(long)(k0 + ty + i * 8) * N + n0 + tx];
  __syncthreads();
#pragma unroll
  for (int i = 0; i < 4; ++i) {
    int r = ty + i * 8;
    Wt[(long)(n0 + r) * K + k0 + tx] = f2bf(tile[tx][r]);
  }
}

// -------- y [16][77][768] f32 -> yp [16][80][768] bf16, pad rows = 0 -------
__global__ __launch_bounds__(256) void cvt_y_pad(const float* __restrict__ y,
                                                 u16* __restrict__ yp) {
  int idx = blockIdx.x * 256 + threadIdx.x;
  int e = idx * 4;  // element index into [16][80][768]
  int c = e % 768;
  int rb = e / 768;
  int r = rb % 80, b = rb / 80;
  ushort4 o;
  if (r < 77) {
    float4 v = *reinterpret_cast<const float4*>(y + ((long)(b * 77 + r) * 768 + c));
    o.x = f2bf(v.x); o.y = f2bf(v.y); o.z = f2bf(v.z); o.w = f2bf(v.w);
  } else {
    o.x = 0; o.y = 0; o.z = 0; o.w = 0;
  }
  *reinterpret_cast<ushort4*>(yp + e) = o;
}

// ================== 256x256 8-phase bf16 GEMM, C = A @ Bt^T + bias =========
// A [M][K] bf16 row-major, Bt [N][K] bf16 row-major, bias [N] f32.
// M % 256 == 0, N % 256 == 0, K % 128 == 0 (nt even). 512 threads, 8 waves.
// T1 XCD swizzle + T2 (chunk^row&7) LDS swizzle + T3/T4 counted vmcnt + T5.
template <bool OUT_BF16>
__global__ __launch_bounds__(512, 2) void gemm8(const u16* __restrict__ A,
                                                const u16* __restrict__ Bt,
                                                const float* __restrict__ bias,
                                                void* __restrict__ Cv,
                                                int M, int N, int K) {
  extern __shared__ __align__(16) u16 lds[];  // 128 KB: A[2][16384], B[2][16384]
  const int tid = threadIdx.x;
  const int lane = tid & 63, wid = tid >> 6;
  const int lr = lane & 15, lk = lane >> 4;
  const int wr = wid >> 2, wc = wid & 3;      // 2 x 4 waves, each owns 128x64 out

  // T1: chunked XCD swizzle (bijective when grid % 8 == 0)
  int flat = blockIdx.x;
  int nb = gridDim.x;
  int widx = flat;
  if ((nb & 7) == 0) {
    int per = nb >> 3;
    widx = (flat & 7) * per + (flat >> 3);
  }
  const int nbx = N >> 8;
  const long m0 = (long)(widx / nbx) * 256;
  const long n0 = (long)(widx % nbx) * 256;
  const int nt = K >> 6;

  f32x4 acc[8][4] = {};

  // staging indices (T2: pre-swizzled global chunk, linear LDS dest)
  const int rb = tid >> 3;            // 0..63
  const int cl = tid & 7;             // LDS 16B-chunk within 128B row
  const int cg = cl ^ (rb & 7);       // global chunk (inverse swizzle)
  const long abase = m0 * (long)K;
  const long bbase = n0 * (long)K;

#define STAGE(t, p)                                                          \
  do {                                                                       \
    long k0_ = (long)(t) * 64;                                               \
    u16* Ad = lds + (p) * 16384;                                             \
    u16* Bd = lds + 32768 + (p) * 16384;                                     \
    _Pragma("unroll")                                                        \
    for (int i_ = 0; i_ < 4; ++i_) {                                         \
      int row_ = i_ * 64 + rb;                                               \
      GLOAD_LDS16(A + abase + (long)row_ * K + k0_ + cg * 8,                 \
                  Ad + row_ * 64 + cl * 8);                                  \
      GLOAD_LDS16(Bt + bbase + (long)row_ * K + k0_ + cg * 8,                \
                  Bd + row_ * 64 + cl * 8);                                  \
    }                                                                        \
  } while (0)

#define LDA(mh)                                                              \
  _Pragma("unroll")                                                          \
  for (int i_ = 0; i_ < 4; ++i_)                                             \
    _Pragma("unroll")                                                        \
    for (int kk_ = 0; kk_ < 2; ++kk_) {                                      \
      int row_ = wr * 128 + ((mh) * 4 + i_) * 16 + lr;                       \
      int ch_ = (kk_ * 4 + lk) ^ (lr & 7);                                   \
      af[i_][kk_] = *reinterpret_cast<const bf16x8*>(Ab + row_ * 64 + ch_ * 8); \
    }

#define LDB(nh)                                                              \
  _Pragma("unroll")                                                          \
  for (int j_ = 0; j_ < 2; ++j_)                                             \
    _Pragma("unroll")                                                        \
    for (int kk_ = 0; kk_ < 2; ++kk_) {                                      \
      int row_ = wc * 64 + ((nh) * 2 + j_) * 16 + lr;                        \
      int ch_ = (kk_ * 4 + lk) ^ (lr & 7);                                   \
      bf[(nh) * 2 + j_][kk_] = *reinterpret_cast<const bf16x8*>(Bb + row_ * 64 + ch_ * 8); \
    }

#define MFMA16(mh, nh)                                                       \
  __builtin_amdgcn_s_setprio(1);                                             \
  _Pragma("unroll")                                                          \
  for (int i_ = 0; i_ < 4; ++i_)                                             \
    _Pragma("unroll")                                                        \
    for (int j_ = 0; j_ < 2; ++j_)                                           \
      _Pragma("unroll")                                                      \
      for (int kk_ = 0; kk_ < 2; ++kk_)                                      \
        acc[(mh) * 4 + i_][(nh) * 2 + j_] =                                  \
            __builtin_amdgcn_mfma_f32_16x16x32_bf16(                         \
                af[i_][kk_], bf[(nh) * 2 + j_][kk_],                         \
                acc[(mh) * 4 + i_][(nh) * 2 + j_], 0, 0, 0);                 \
  __builtin_amdgcn_s_setprio(0);

  // prologue: tiles 0,1 in flight; wait tile 0 (8 loads still outstanding)
  STAGE(0, 0);
  STAGE(1, 1);
  VMCNT(8);
  BAR();

  for (int t = 0; t < nt; ++t) {
    const int p = t & 1;
    const u16* Ab = lds + p * 16384;
    const u16* Bb = lds + 32768 + p * 16384;
    bf16x8 af[4][2], bf[4][2];

    LDA(0); LDB(0);
    BAR(); MFMA16(0, 0);
    BAR(); LDB(1);
    BAR(); MFMA16(0, 1);
    BAR(); LDA(1);
    BAR(); MFMA16(1, 1);
    BAR(); MFMA16(1, 0);
    if (t == nt - 1) break;
    BAR();                                   // all waves done reading parity p
    if (t + 2 < nt) { STAGE(t + 2, p); VMCNT(8); }  // tile t+1 landed, t+2 in flight
    else { VMCNT(0); }                        // tail drain
    BAR();
  }

  // epilogue: C write (+bias); bf16 path packs 4 cols -> 8B stores via shfl
  const long mrow = m0 + wr * 128;
  const long ncol = n0 + wc * 64;
#pragma unroll
  for (int n = 0; n < 4; ++n) {
    long col = ncol + n * 16 + lr;
    float bb = bias[col];
    if (OUT_BF16) {
#pragma unroll
      for (int m = 0; m < 8; ++m)
#pragma unroll
        for (int j = 0; j < 4; ++j) {
          long row = mrow + m * 16 + lk * 4 + j;
          unsigned h = f2bf(acc[m][n][j] + bb);
          unsigned ph = h | (((unsigned)__shfl_xor((int)h, 1, 64)) << 16);
          unsigned p2 = (unsigned)__shfl_xor((int)ph, 2, 64);
          if ((lane & 3) == 0) {
            uint2 o; o.x = ph; o.y = p2;
            *reinterpret_cast<uint2*>((u16*)Cv + row * N + col) = o;
          }
        }
    } else {
#pragma unroll
      for (int m = 0; m < 8; ++m)
#pragma unroll
        for (int j = 0; j < 4; ++j) {
          long row = mrow + m * 16 + lk * 4 + j;
          ((float*)Cv)[row * N + col] = acc[m][n][j] + bb;
        }
    }
  }
#undef STAGE
#undef LDA
#undef LDB
#undef MFMA16
}

// ---------------- fused attention: 16 q-rows per block, in-place on Q ------
__global__ __launch_bounds__(256) void attn_fused(u16* __restrict__ Q,
                                                  const u16* __restrict__ Kp,
                                                  const u16* __restrict__ Vp) {
  const int blk = blockIdx.x;
  const int b = blk >> 8;               // 256 blocks per batch (4096/16)
  const int q0 = (blk & 255) << 4;
  const long qoff = ((long)b * 4096 + q0) * 1024;
  const int tid = threadIdx.x;
  const int lane = tid & 63, wave = tid >> 6;
  const int lr = lane & 15, lk = lane >> 4;

  __shared__ float S4[4][16][80];
  __shared__ __align__(16) float Pt[80][16];

  // Phase 1: scores via MFMA; wave w covers k = w*256 .. w*256+255
  f32x4 acc[5] = {};
  const u16* qb = Q + qoff;
  const u16* kb = Kp + (long)b * 80 * 1024;
#pragma unroll
  for (int t = 0; t < 8; ++t) {
    int kk = wave * 8 + t;
    bf16x8 qa = *reinterpret_cast<const bf16x8*>(qb + lr * 1024 + kk * 32 + lk * 8);
#pragma unroll
    for (int n = 0; n < 5; ++n) {
      bf16x8 kf = *reinterpret_cast<const bf16x8*>(kb + (n * 16 + lr) * 1024 + kk * 32 + lk * 8);
      acc[n] = __builtin_amdgcn_mfma_f32_16x16x32_bf16(qa, kf, acc[n], 0, 0, 0);
    }
  }
#pragma unroll
  for (int n = 0; n < 5; ++n)
#pragma unroll
    for (int j = 0; j < 4; ++j)
      S4[wave][lk * 4 + j][n * 16 + lr] = acc[n][j];
  __syncthreads();

  // Phase 2: cross-wave reduce + softmax (row r handled by 16 threads)
  {
    const int r = tid >> 4, ci = tid & 15;
    const float scale = 0.088388347648318447f;  // 1/sqrt(128)
    float v[5];
    float mx = -3e38f;
#pragma unroll
    for (int i = 0; i < 5; ++i) {
      int c = ci + 16 * i;
      float s = (S4[0][r][c] + S4[1][r][c]) + (S4[2][r][c] + S4[3][r][c]);
      s *= scale;
      if (c >= 77) s = -3e38f;
      v[i] = s;
      mx = fmaxf(mx, s);
    }
#pragma unroll
    for (int off = 1; off < 16; off <<= 1) mx = fmaxf(mx, __shfl_xor(mx, off, 64));
    float sum = 0.f, e[5];
#pragma unroll
    for (int i = 0; i < 5; ++i) { e[i] = __expf(v[i] - mx); sum += e[i]; }
#pragma unroll
    for (int off = 1; off < 16; off <<= 1) sum += __shfl_xor(sum, off, 64);
    float inv = 1.f / sum;
#pragma unroll
    for (int i = 0; i < 5; ++i) Pt[ci + 16 * i][r] = e[i] * inv;  // transposed
  }
  __syncthreads();

  // Phase 3: PV (vector f32). Each thread: 4 e-cols x 16 q-rows.
  float oacc[16][4] = {};
  const u16* vb = Vp + (long)b * 80 * 1024 + tid * 4;
  for (int k = 0; k < 80; ++k) {
    ushort4 vv = *reinterpret_cast<const ushort4*>(vb + k * 1024);
    float vf0 = bf2f(vv.x), vf1 = bf2f(vv.y), vf2 = bf2f(vv.z), vf3 = bf2f(vv.w);
    f32x4 pp[4];
    pp[0] = *reinterpret_cast<const f32x4*>(&Pt[k][0]);
    pp[1] = *reinterpret_cast<const f32x4*>(&Pt[k][4]);
    pp[2] = *reinterpret_cast<const f32x4*>(&Pt[k][8]);
    pp[3] = *reinterpret_cast<const f32x4*>(&Pt[k][12]);
#pragma unroll
    for (int q = 0; q < 16; ++q) {
      float pq = pp[q >> 2][q & 3];
      oacc[q][0] += pq * vf0;
      oacc[q][1] += pq * vf1;
      oacc[q][2] += pq * vf2;
      oacc[q][3] += pq * vf3;
    }
  }
  u16* ob = Q + qoff + tid * 4;
#pragma unroll
  for (int q = 0; q < 16; ++q) {
    ushort4 o;
    o.x = f2bf(oacc[q][0]); o.y = f2bf(oacc[q][1]);
    o.z = f2bf(oacc[q][2]); o.w = f2bf(oacc[q][3]);
    *reinterpret_cast<ushort4*>(ob + q * 1024) = o;
  }
}

extern "C" void kernel_launch(void* const* d_in, const int* in_sizes, int n_in,
                              void* d_out, int out_size, void* d_ws, size_t ws_size,
                              hipStream_t stream) {
  const float* x  = (const float*)d_in[0];
  const float* y  = (const float*)d_in[1];
  const float* Wq = (const float*)d_in[2];
  const float* bq = (const float*)d_in[3];
  const float* Wk = (const float*)d_in[4];
  const float* bk = (const float*)d_in[5];
  const float* Wv = (const float*)d_in[6];
  const float* bv = (const float*)d_in[7];
  const float* Wo = (const float*)d_in[8];
  const float* bo = (const float*)d_in[9];

  const int B = 16, Lq = 4096, D = 1024, Dc = 768, Lp = 80;
  const long Mq = (long)B * Lq;  // 65536

  char* p = (char*)d_ws;
  u16* Qb  = (u16*)p; p += (size_t)Mq * D * 2;      // Q, then attn out (in-place)
  u16* Wqt = (u16*)p; p += (size_t)D * D * 2;
  u16* Wkt = (u16*)p; p += (size_t)D * Dc * 2;      // [1024][768]
  u16* Wvt = (u16*)p; p += (size_t)D * Dc * 2;
  u16* Wot = (u16*)p; p += (size_t)D * D * 2;
  u16* yp  = (u16*)p; p += (size_t)B * Lp * Dc * 2; // [16][80][768], pad zeroed
  u16* Kp  = (u16*)p; p += (size_t)B * Lp * D * 2;  // [16][80][1024]
  u16* Vp  = (u16*)p; p += (size_t)B * Lp * D * 2;
  u16* xb  = (u16*)d_out;  // scratch: x as bf16 lives in d_out until final GEMM

  // allow 128 KB dynamic LDS for the GEMM (idempotent host call)
  (void)hipFuncSetAttribute(reinterpret_cast<const void*>(&gemm8<true>),
                            hipFuncAttributeMaxDynamicSharedMemorySize, 131072);
  (void)hipFuncSetAttribute(reinterpret_cast<const void*>(&gemm8<false>),
                            hipFuncAttributeMaxDynamicSharedMemorySize, 131072);

  // conversions
  cvt_f32_bf16<<<(int)(Mq * D / 1024), 256, 0, stream>>>(x, xb, Mq * D / 4);
  transpose_cvt<<<dim3(D / 32, D / 32), 256, 0, stream>>>(Wq, Wqt, D, D);
  transpose_cvt<<<dim3(D / 32, Dc / 32), 256, 0, stream>>>(Wk, Wkt, Dc, D);
  transpose_cvt<<<dim3(D / 32, Dc / 32), 256, 0, stream>>>(Wv, Wvt, Dc, D);
  transpose_cvt<<<dim3(D / 32, D / 32), 256, 0, stream>>>(Wo, Wot, D, D);
  cvt_y_pad<<<(B * Lp * Dc / 4) / 256, 256, 0, stream>>>(y, yp);

  // K/V projections: [1280][768] @ [768][1024] -> [1280][1024]
  gemm8<true><<<(1280 / 256) * (D / 256), 512, 131072, stream>>>(yp, Wkt, bk, Kp, B * Lp, D, Dc);
  gemm8<true><<<(1280 / 256) * (D / 256), 512, 131072, stream>>>(yp, Wvt, bv, Vp, B * Lp, D, Dc);

  // Q projection: [65536][1024] @ [1024][1024] -> [65536][1024] bf16
  gemm8<true><<<(int)(Mq / 256) * (D / 256), 512, 131072, stream>>>(xb, Wqt, bq, Qb, (int)Mq, D, D);

  // fused attention, writes back into Qb
  attn_fused<<<(int)(Mq / 16), 256, 0, stream>>>(Qb, Kp, Vp);

  // output projection: [65536][1024] @ [1024][1024] -> d_out f32
  gemm8<false><<<(int)(Mq / 256) * (D / 256), 512, 131072, stream>>>(Qb, Wot, bo, d_out, (int)Mq, D, D);
}

// Round 3
// 694.458 us; speedup vs baseline: 1.1463x; 1.0881x over previous
//
#include <hip/hip_runtime.h>

typedef unsigned short u16;
typedef __bf16 bf16x8 __attribute__((ext_vector_type(8)));
typedef float f32x4 __attribute__((ext_vector_type(4)));

static __device__ __forceinline__ u16 f2bf(float f) {
  unsigned u = __builtin_bit_cast(unsigned, f);
  u = u + 0x7FFFu + ((u >> 16) & 1u);   // RNE
  return (u16)(u >> 16);
}
static __device__ __forceinline__ float bf2f(u16 h) {
  return __builtin_bit_cast(float, (unsigned)h << 16);
}

#define GLOAD_LDS16(g, l) __builtin_amdgcn_global_load_lds(              \
    (const __attribute__((address_space(1))) void*)(g),                  \
    (__attribute__((address_space(3))) void*)(l), 16, 0, 0)
#define BAR() asm volatile("s_barrier" ::: "memory")
#define VMCNT(n) asm volatile("s_waitcnt vmcnt(" #n ")" ::: "memory")
#define LGKM0() do { asm volatile("s_waitcnt lgkmcnt(0)" ::: "memory");   \
                     __builtin_amdgcn_sched_barrier(0); } while (0)

// ---------------- elementwise f32 -> bf16 (4 elems/thread) ----------------
__global__ __launch_bounds__(256) void cvt_f32_bf16(const float* __restrict__ in,
                                                    u16* __restrict__ out, long n4) {
  long i = (long)blockIdx.x * 256 + threadIdx.x;
  if (i >= n4) return;
  float4 v = reinterpret_cast<const float4*>(in)[i];
  ushort4 o;
  o.x = f2bf(v.x); o.y = f2bf(v.y); o.z = f2bf(v.z); o.w = f2bf(v.w);
  reinterpret_cast<ushort4*>(out)[i] = o;
}

// ------------- transpose + convert: W[K][N] f32 -> Wt[N][K] bf16 ----------
__global__ __launch_bounds__(256) void transpose_cvt(const float* __restrict__ W,
                                                     u16* __restrict__ Wt,
                                                     int K, int N) {
  __shared__ float tile[32][33];
  const int tx = threadIdx.x & 31, ty = threadIdx.x >> 5;  // ty: 0..7
  const int n0 = blockIdx.x * 32, k0 = blockIdx.y * 32;
#pragma unroll
  for (int i = 0; i < 4; ++i)
    tile[ty + i * 8][tx] = W[(long)(k0 + ty + i * 8) * N + n0 + tx];
  __syncthreads();
#pragma unroll
  for (int i = 0; i < 4; ++i) {
    int r = ty + i * 8;
    Wt[(long)(n0 + r) * K + k0 + tx] = f2bf(tile[tx][r]);
  }
}

// -------- y [16][77][768] f32 -> yp [16][80][768] bf16, pad rows = 0 -------
__global__ __launch_bounds__(256) void cvt_y_pad(const float* __restrict__ y,
                                                 u16* __restrict__ yp) {
  int idx = blockIdx.x * 256 + threadIdx.x;
  int e = idx * 4;  // element index into [16][80][768]
  int c = e % 768;
  int rb = e / 768;
  int r = rb % 80, b = rb / 80;
  ushort4 o;
  if (r < 77) {
    float4 v = *reinterpret_cast<const float4*>(y + ((long)(b * 77 + r) * 768 + c));
    o.x = f2bf(v.x); o.y = f2bf(v.y); o.z = f2bf(v.z); o.w = f2bf(v.w);
  } else {
    o.x = 0; o.y = 0; o.z = 0; o.w = 0;
  }
  *reinterpret_cast<ushort4*>(yp + e) = o;
}

// ============ 256x256 m201-style 8-phase bf16 GEMM, C = A @ Bt^T + bias ====
// A [M][K] bf16 row-major, Bt [N][K] bf16 row-major, bias [N] f32.
// M % 256 == 0, N % 256 == 0, K % 128 == 0 (nt even, nt >= 4).
// 512 threads = 8 waves (2M x 4N), per-wave output 128x64.
// LDS 128 KB: A[2 parity][256][64] u16, B[2 parity][256][64] u16.
// Per iteration: 2 K-tiles x 4 quadrant-phases; each phase stages exactly one
// half-tile (2 x global_load_lds dwordx4); vmcnt(4) at phases 4 and 8 only.
template <bool OUT_BF16>
__global__ __launch_bounds__(512, 2) void gemm8(const u16* __restrict__ A,
                                                const u16* __restrict__ Bt,
                                                const float* __restrict__ bias,
                                                void* __restrict__ Cv,
                                                int M, int N, int K) {
  extern __shared__ __align__(16) u16 lds[];
  const int tid = threadIdx.x;
  const int lane = tid & 63, wid = tid >> 6;
  const int lr = lane & 15, lk = lane >> 4;
  const int wr = wid >> 2, wc = wid & 3;

  // T1: chunked XCD swizzle (bijective when grid % 8 == 0)
  int flat = blockIdx.x;
  int nb = gridDim.x;
  int widx = flat;
  if ((nb & 7) == 0) {
    int per = nb >> 3;
    widx = (flat & 7) * per + (flat >> 3);
  }
  const int nbx = N >> 8;
  const long m0 = (long)(widx / nbx) * 256;
  const long n0 = (long)(widx % nbx) * 256;
  const int nt = K >> 6;

  f32x4 acc[8][4] = {};

  const long abase = m0 * (long)K;
  const long bbase = n0 * (long)K;
  const int srl = tid >> 3;   // staging row within 64-row group
  const int scl = tid & 7;    // staging LDS 16B-chunk within 128B row

  // T2 swizzle: LDS chunk cl of row r holds global chunk cl ^ (r&7).
#define STAGE_HALF(SRC, sbase, t_, half_, ldsbase)                           \
  do {                                                                       \
    long k0_ = (long)(t_) * 64;                                              \
    _Pragma("unroll")                                                        \
    for (int j_ = 0; j_ < 2; ++j_) {                                         \
      int row_ = (half_) * 128 + j_ * 64 + srl;                              \
      int cg_ = scl ^ (row_ & 7);                                            \
      GLOAD_LDS16(SRC + (sbase) + (long)row_ * K + k0_ + cg_ * 8,            \
                  lds + (ldsbase) + row_ * 64 + scl * 8);                    \
    }                                                                        \
  } while (0)

#define LDB_ALL(p)                                                           \
  _Pragma("unroll")                                                          \
  for (int n_ = 0; n_ < 4; ++n_)                                             \
    _Pragma("unroll")                                                        \
    for (int kk_ = 0; kk_ < 2; ++kk_) {                                      \
      int row_ = wc * 64 + n_ * 16 + lr;                                     \
      int ch_ = (kk_ * 4 + lk) ^ (lr & 7);                                   \
      bq[n_][kk_] = *reinterpret_cast<const bf16x8*>(                        \
          lds + 32768 + (p) * 16384 + row_ * 64 + ch_ * 8);                  \
    }

#define LDA_Q(p, q)                                                          \
  _Pragma("unroll")                                                          \
  for (int i_ = 0; i_ < 2; ++i_)                                             \
    _Pragma("unroll")                                                        \
    for (int kk_ = 0; kk_ < 2; ++kk_) {                                      \
      int row_ = wr * 128 + ((q) * 2 + i_) * 16 + lr;                        \
      int ch_ = (kk_ * 4 + lk) ^ (lr & 7);                                   \
      af[i_][kk_] = *reinterpret_cast<const bf16x8*>(                        \
          lds + (p) * 16384 + row_ * 64 + ch_ * 8);                          \
    }

#define MFMA_Q(q)                                                            \
  __builtin_amdgcn_s_setprio(1);                                             \
  _Pragma("unroll")                                                          \
  for (int i_ = 0; i_ < 2; ++i_)                                             \
    _Pragma("unroll")                                                        \
    for (int n_ = 0; n_ < 4; ++n_)                                           \
      _Pragma("unroll")                                                      \
      for (int kk_ = 0; kk_ < 2; ++kk_)                                      \
        acc[(q) * 2 + i_][n_] = __builtin_amdgcn_mfma_f32_16x16x32_bf16(     \
            af[i_][kk_], bq[n_][kk_], acc[(q) * 2 + i_][n_], 0, 0, 0);       \
  __builtin_amdgcn_s_setprio(0);

  // prologue: A(0), B(0) fully staged; B(1) in flight behind them
  STAGE_HALF(A, abase, 0, 0, 0);
  STAGE_HALF(A, abase, 0, 1, 0);
  STAGE_HALF(Bt, bbase, 0, 0, 32768);
  STAGE_HALF(Bt, bbase, 0, 1, 32768);
  STAGE_HALF(Bt, bbase, 1, 0, 49152);
  STAGE_HALF(Bt, bbase, 1, 1, 49152);
  VMCNT(4);   // tile-0 A+B landed; B(1)'s 4 loads may remain in flight
  BAR();

  const int niter = nt >> 1;
  for (int tp = 0; tp < niter; ++tp) {
    const int T = tp << 1;
    const bool more = (T + 2 < nt);
    bf16x8 af[2][2], bq[4][2];

    // ---- tile T (parity 0) ----
    // ph1
    LDB_ALL(0); LDA_Q(0, 0);
    STAGE_HALF(A, abase, T + 1, 0, 16384);
    BAR(); LGKM0(); MFMA_Q(0); BAR();
    // ph2
    LDA_Q(0, 1);
    STAGE_HALF(A, abase, T + 1, 1, 16384);
    BAR(); LGKM0(); MFMA_Q(1); BAR();
    // ph3
    LDA_Q(0, 2);
    if (more) STAGE_HALF(Bt, bbase, T + 2, 0, 32768);
    BAR(); LGKM0(); MFMA_Q(2); BAR();
    // ph4
    LDA_Q(0, 3);
    if (more) { STAGE_HALF(Bt, bbase, T + 2, 1, 32768); VMCNT(4); }
    else VMCNT(0);
    BAR(); LGKM0(); MFMA_Q(3); BAR();

    // ---- tile T+1 (parity 1) ----
    // ph5
    LDB_ALL(1); LDA_Q(1, 0);
    if (more) STAGE_HALF(A, abase, T + 2, 0, 0);
    BAR(); LGKM0(); MFMA_Q(0); BAR();
    // ph6
    LDA_Q(1, 1);
    if (more) STAGE_HALF(A, abase, T + 2, 1, 0);
    BAR(); LGKM0(); MFMA_Q(1); BAR();
    // ph7
    LDA_Q(1, 2);
    if (more) STAGE_HALF(Bt, bbase, T + 3, 0, 49152);
    BAR(); LGKM0(); MFMA_Q(2); BAR();
    // ph8
    LDA_Q(1, 3);
    if (more) { STAGE_HALF(Bt, bbase, T + 3, 1, 49152); VMCNT(4); }
    BAR(); LGKM0(); MFMA_Q(3); BAR();
  }

  // epilogue: C write (+bias); bf16 path packs 4 cols -> 8B stores via shfl
  const long mrow = m0 + wr * 128;
  const long ncol = n0 + wc * 64;
#pragma unroll
  for (int n = 0; n < 4; ++n) {
    long col = ncol + n * 16 + lr;
    float bb = bias[col];
    if (OUT_BF16) {
#pragma unroll
      for (int m = 0; m < 8; ++m)
#pragma unroll
        for (int j = 0; j < 4; ++j) {
          long row = mrow + m * 16 + lk * 4 + j;
          unsigned h = f2bf(acc[m][n][j] + bb);
          unsigned ph = h | (((unsigned)__shfl_xor((int)h, 1, 64)) << 16);
          unsigned p2 = (unsigned)__shfl_xor((int)ph, 2, 64);
          if ((lane & 3) == 0) {
            uint2 o; o.x = ph; o.y = p2;
            *reinterpret_cast<uint2*>((u16*)Cv + row * N + col) = o;
          }
        }
    } else {
#pragma unroll
      for (int m = 0; m < 8; ++m)
#pragma unroll
        for (int j = 0; j < 4; ++j) {
          long row = mrow + m * 16 + lk * 4 + j;
          ((float*)Cv)[row * N + col] = acc[m][n][j] + bb;
        }
    }
  }
#undef STAGE_HALF
#undef LDB_ALL
#undef LDA_Q
#undef MFMA_Q
}

// ---------------- fused attention: 16 q-rows per block, in-place on Q ------
__global__ __launch_bounds__(256) void attn_fused(u16* __restrict__ Q,
                                                  const u16* __restrict__ Kp,
                                                  const u16* __restrict__ Vp) {
  const int blk = blockIdx.x;
  const int b = blk >> 8;               // 256 blocks per batch (4096/16)
  const int q0 = (blk & 255) << 4;
  const long qoff = ((long)b * 4096 + q0) * 1024;
  const int tid = threadIdx.x;
  const int lane = tid & 63, wave = tid >> 6;
  const int lr = lane & 15, lk = lane >> 4;

  __shared__ float S4[4][16][80];
  __shared__ __align__(16) float Pt[80][16];

  // Phase 1: scores via MFMA; wave w covers k = w*256 .. w*256+255
  f32x4 acc[5] = {};
  const u16* qb = Q + qoff;
  const u16* kb = Kp + (long)b * 80 * 1024;
#pragma unroll
  for (int t = 0; t < 8; ++t) {
    int kk = wave * 8 + t;
    bf16x8 qa = *reinterpret_cast<const bf16x8*>(qb + lr * 1024 + kk * 32 + lk * 8);
#pragma unroll
    for (int n = 0; n < 5; ++n) {
      bf16x8 kf = *reinterpret_cast<const bf16x8*>(kb + (n * 16 + lr) * 1024 + kk * 32 + lk * 8);
      acc[n] = __builtin_amdgcn_mfma_f32_16x16x32_bf16(qa, kf, acc[n], 0, 0, 0);
    }
  }
#pragma unroll
  for (int n = 0; n < 5; ++n)
#pragma unroll
    for (int j = 0; j < 4; ++j)
      S4[wave][lk * 4 + j][n * 16 + lr] = acc[n][j];
  __syncthreads();

  // Phase 2: cross-wave reduce + softmax (row r handled by 16 threads)
  {
    const int r = tid >> 4, ci = tid & 15;
    const float scale = 0.088388347648318447f;  // 1/sqrt(128)
    float v[5];
    float mx = -3e38f;
#pragma unroll
    for (int i = 0; i < 5; ++i) {
      int c = ci + 16 * i;
      float s = (S4[0][r][c] + S4[1][r][c]) + (S4[2][r][c] + S4[3][r][c]);
      s *= scale;
      if (c >= 77) s = -3e38f;
      v[i] = s;
      mx = fmaxf(mx, s);
    }
#pragma unroll
    for (int off = 1; off < 16; off <<= 1) mx = fmaxf(mx, __shfl_xor(mx, off, 64));
    float sum = 0.f, e[5];
#pragma unroll
    for (int i = 0; i < 5; ++i) { e[i] = __expf(v[i] - mx); sum += e[i]; }
#pragma unroll
    for (int off = 1; off < 16; off <<= 1) sum += __shfl_xor(sum, off, 64);
    float inv = 1.f / sum;
#pragma unroll
    for (int i = 0; i < 5; ++i) Pt[ci + 16 * i][r] = e[i] * inv;  // transposed
  }
  __syncthreads();

  // Phase 3: PV (vector f32). Each thread: 4 e-cols x 16 q-rows.
  float oacc[16][4] = {};
  const u16* vb = Vp + (long)b * 80 * 1024 + tid * 4;
  for (int k = 0; k < 80; ++k) {
    ushort4 vv = *reinterpret_cast<const ushort4*>(vb + k * 1024);
    float vf0 = bf2f(vv.x), vf1 = bf2f(vv.y), vf2 = bf2f(vv.z), vf3 = bf2f(vv.w);
    f32x4 pp[4];
    pp[0] = *reinterpret_cast<const f32x4*>(&Pt[k][0]);
    pp[1] = *reinterpret_cast<const f32x4*>(&Pt[k][4]);
    pp[2] = *reinterpret_cast<const f32x4*>(&Pt[k][8]);
    pp[3] = *reinterpret_cast<const f32x4*>(&Pt[k][12]);
#pragma unroll
    for (int q = 0; q < 16; ++q) {
      float pq = pp[q >> 2][q & 3];
      oacc[q][0] += pq * vf0;
      oacc[q][1] += pq * vf1;
      oacc[q][2] += pq * vf2;
      oacc[q][3] += pq * vf3;
    }
  }
  u16* ob = Q + qoff + tid * 4;
#pragma unroll
  for (int q = 0; q < 16; ++q) {
    ushort4 o;
    o.x = f2bf(oacc[q][0]); o.y = f2bf(oacc[q][1]);
    o.z = f2bf(oacc[q][2]); o.w = f2bf(oacc[q][3]);
    *reinterpret_cast<ushort4*>(ob + q * 1024) = o;
  }
}

extern "C" void kernel_launch(void* const* d_in, const int* in_sizes, int n_in,
                              void* d_out, int out_size, void* d_ws, size_t ws_size,
                              hipStream_t stream) {
  const float* x  = (const float*)d_in[0];
  const float* y  = (const float*)d_in[1];
  const float* Wq = (const float*)d_in[2];
  const float* bq = (const float*)d_in[3];
  const float* Wk = (const float*)d_in[4];
  const float* bk = (const float*)d_in[5];
  const float* Wv = (const float*)d_in[6];
  const float* bv = (const float*)d_in[7];
  const float* Wo = (const float*)d_in[8];
  const float* bo = (const float*)d_in[9];

  const int B = 16, Lq = 4096, D = 1024, Dc = 768, Lp = 80;
  const long Mq = (long)B * Lq;  // 65536

  char* p = (char*)d_ws;
  u16* Qb  = (u16*)p; p += (size_t)Mq * D * 2;      // Q, then attn out (in-place)
  u16* Wqt = (u16*)p; p += (size_t)D * D * 2;
  u16* Wkt = (u16*)p; p += (size_t)D * Dc * 2;      // [1024][768]
  u16* Wvt = (u16*)p; p += (size_t)D * Dc * 2;
  u16* Wot = (u16*)p; p += (size_t)D * D * 2;
  u16* yp  = (u16*)p; p += (size_t)B * Lp * Dc * 2; // [16][80][768], pad zeroed
  u16* Kp  = (u16*)p; p += (size_t)B * Lp * D * 2;  // [16][80][1024]
  u16* Vp  = (u16*)p; p += (size_t)B * Lp * D * 2;
  u16* xb  = (u16*)d_out;  // scratch: x as bf16 lives in d_out until final GEMM

  // allow 128 KB dynamic LDS for the GEMM (idempotent host call)
  (void)hipFuncSetAttribute(reinterpret_cast<const void*>(&gemm8<true>),
                            hipFuncAttributeMaxDynamicSharedMemorySize, 131072);
  (void)hipFuncSetAttribute(reinterpret_cast<const void*>(&gemm8<false>),
                            hipFuncAttributeMaxDynamicSharedMemorySize, 131072);

  // conversions
  cvt_f32_bf16<<<(int)(Mq * D / 1024), 256, 0, stream>>>(x, xb, Mq * D / 4);
  transpose_cvt<<<dim3(D / 32, D / 32), 256, 0, stream>>>(Wq, Wqt, D, D);
  transpose_cvt<<<dim3(D / 32, Dc / 32), 256, 0, stream>>>(Wk, Wkt, Dc, D);
  transpose_cvt<<<dim3(D / 32, Dc / 32), 256, 0, stream>>>(Wv, Wvt, Dc, D);
  transpose_cvt<<<dim3(D / 32, D / 32), 256, 0, stream>>>(Wo, Wot, D, D);
  cvt_y_pad<<<(B * Lp * Dc / 4) / 256, 256, 0, stream>>>(y, yp);

  // K/V projections: [1280][768] @ [768][1024] -> [1280][1024]
  gemm8<true><<<(1280 / 256) * (D / 256), 512, 131072, stream>>>(yp, Wkt, bk, Kp, B * Lp, D, Dc);
  gemm8<true><<<(1280 / 256) * (D / 256), 512, 131072, stream>>>(yp, Wvt, bv, Vp, B * Lp, D, Dc);

  // Q projection: [65536][1024] @ [1024][1024] -> [65536][1024] bf16
  gemm8<true><<<(int)(Mq / 256) * (D / 256), 512, 131072, stream>>>(xb, Wqt, bq, Qb, (int)Mq, D, D);

  // fused attention, writes back into Qb
  attn_fused<<<(int)(Mq / 16), 256, 0, stream>>>(Qb, Kp, Vp);

  // output projection: [65536][1024] @ [1024][1024] -> d_out f32
  gemm8<false><<<(int)(Mq / 256) * (D / 256), 512, 131072, stream>>>(Qb, Wot, bo, d_out, (int)Mq, D, D);
}

// Round 4
// 674.118 us; speedup vs baseline: 1.1809x; 1.0302x over previous
//
#include <hip/hip_runtime.h>

typedef unsigned short u16;
typedef __bf16 bf16x8 __attribute__((ext_vector_type(8)));
typedef float f32x4 __attribute__((ext_vector_type(4)));

static __device__ __forceinline__ u16 f2bf(float f) {
  unsigned u = __builtin_bit_cast(unsigned, f);
  u = u + 0x7FFFu + ((u >> 16) & 1u);   // RNE
  return (u16)(u >> 16);
}
static __device__ __forceinline__ float bf2f(u16 h) {
  return __builtin_bit_cast(float, (unsigned)h << 16);
}

#define GLOAD_LDS16(g, l) __builtin_amdgcn_global_load_lds(              \
    (const __attribute__((address_space(1))) void*)(g),                  \
    (__attribute__((address_space(3))) void*)(l), 16, 0, 0)
#define BAR() asm volatile("s_barrier" ::: "memory")
#define VMCNT(n) asm volatile("s_waitcnt vmcnt(" #n ")" ::: "memory")
#define LGKM0() do { asm volatile("s_waitcnt lgkmcnt(0)" ::: "memory");   \
                     __builtin_amdgcn_sched_barrier(0); } while (0)

// ---------------- elementwise f32 -> bf16 (4 elems/thread) ----------------
__global__ __launch_bounds__(256) void cvt_f32_bf16(const float* __restrict__ in,
                                                    u16* __restrict__ out, long n4) {
  long i = (long)blockIdx.x * 256 + threadIdx.x;
  if (i >= n4) return;
  float4 v = reinterpret_cast<const float4*>(in)[i];
  ushort4 o;
  o.x = f2bf(v.x); o.y = f2bf(v.y); o.z = f2bf(v.z); o.w = f2bf(v.w);
  reinterpret_cast<ushort4*>(out)[i] = o;
}

// ------------- transpose + convert: W[K][N] f32 -> Wt[N][K] bf16 ----------
__global__ __launch_bounds__(256) void transpose_cvt(const float* __restrict__ W,
                                                     u16* __restrict__ Wt,
                                                     int K, int N) {
  __shared__ float tile[32][33];
  const int tx = threadIdx.x & 31, ty = threadIdx.x >> 5;  // ty: 0..7
  const int n0 = blockIdx.x * 32, k0 = blockIdx.y * 32;
#pragma unroll
  for (int i = 0; i < 4; ++i)
    tile[ty + i * 8][tx] = W[(long)(k0 + ty + i * 8) * N + n0 + tx];
  __syncthreads();
#pragma unroll
  for (int i = 0; i < 4; ++i) {
    int r = ty + i * 8;
    Wt[(long)(n0 + r) * K + k0 + tx] = f2bf(tile[tx][r]);
  }
}

// -------- y [16][77][768] f32 -> yp [16][80][768] bf16, pad rows = 0 -------
__global__ __launch_bounds__(256) void cvt_y_pad(const float* __restrict__ y,
                                                 u16* __restrict__ yp) {
  int idx = blockIdx.x * 256 + threadIdx.x;
  int e = idx * 4;  // element index into [16][80][768]
  int c = e % 768;
  int rb = e / 768;
  int r = rb % 80, b = rb / 80;
  ushort4 o;
  if (r < 77) {
    float4 v = *reinterpret_cast<const float4*>(y + ((long)(b * 77 + r) * 768 + c));
    o.x = f2bf(v.x); o.y = f2bf(v.y); o.z = f2bf(v.z); o.w = f2bf(v.w);
  } else {
    o.x = 0; o.y = 0; o.z = 0; o.w = 0;
  }
  *reinterpret_cast<ushort4*>(yp + e) = o;
}

// ---- Vp [16][80][1024] bf16 -> Vt [16][1024][96] bf16 (k >= 80 zeroed) ----
__global__ __launch_bounds__(256) void transpose_v(const u16* __restrict__ Vp,
                                                   u16* __restrict__ Vt) {
  __shared__ u16 tile[32][34];
  const int tx = threadIdx.x & 31, ty = threadIdx.x >> 5;  // ty: 0..7
  const int b = blockIdx.z;
  const int k0 = blockIdx.y * 32;   // 0,32,64
  const int e0 = blockIdx.x * 32;
  const u16* src = Vp + (long)b * 80 * 1024;
#pragma unroll
  for (int i = 0; i < 4; ++i) {
    int k = k0 + ty + i * 8;
    tile[ty + i * 8][tx] = (k < 80) ? src[(long)k * 1024 + e0 + tx] : (u16)0;
  }
  __syncthreads();
  u16* dst = Vt + (long)b * 1024 * 96;
#pragma unroll
  for (int i = 0; i < 4; ++i) {
    int e = e0 + ty + i * 8;
    dst[(long)e * 96 + k0 + tx] = tile[tx][ty + i * 8];
  }
}

// ============ 256x256 m201-style 8-phase bf16 GEMM, C = A @ Bt^T + bias ====
template <bool OUT_BF16>
__global__ __launch_bounds__(512, 2) void gemm8(const u16* __restrict__ A,
                                                const u16* __restrict__ Bt,
                                                const float* __restrict__ bias,
                                                void* __restrict__ Cv,
                                                int M, int N, int K) {
  extern __shared__ __align__(16) u16 lds[];
  const int tid = threadIdx.x;
  const int lane = tid & 63, wid = tid >> 6;
  const int lr = lane & 15, lk = lane >> 4;
  const int wr = wid >> 2, wc = wid & 3;

  // T1: chunked XCD swizzle (bijective when grid % 8 == 0)
  int flat = blockIdx.x;
  int nb = gridDim.x;
  int widx = flat;
  if ((nb & 7) == 0) {
    int per = nb >> 3;
    widx = (flat & 7) * per + (flat >> 3);
  }
  const int nbx = N >> 8;
  const long m0 = (long)(widx / nbx) * 256;
  const long n0 = (long)(widx % nbx) * 256;
  const int nt = K >> 6;

  f32x4 acc[8][4] = {};

  const long abase = m0 * (long)K;
  const long bbase = n0 * (long)K;
  const int srl = tid >> 3;
  const int scl = tid & 7;

#define STAGE_HALF(SRC, sbase, t_, half_, ldsbase)                           \
  do {                                                                       \
    long k0_ = (long)(t_) * 64;                                              \
    _Pragma("unroll")                                                        \
    for (int j_ = 0; j_ < 2; ++j_) {                                         \
      int row_ = (half_) * 128 + j_ * 64 + srl;                              \
      int cg_ = scl ^ (row_ & 7);                                            \
      GLOAD_LDS16(SRC + (sbase) + (long)row_ * K + k0_ + cg_ * 8,            \
                  lds + (ldsbase) + row_ * 64 + scl * 8);                    \
    }                                                                        \
  } while (0)

#define LDB_ALL(p)                                                           \
  _Pragma("unroll")                                                          \
  for (int n_ = 0; n_ < 4; ++n_)                                             \
    _Pragma("unroll")                                                        \
    for (int kk_ = 0; kk_ < 2; ++kk_) {                                      \
      int row_ = wc * 64 + n_ * 16 + lr;                                     \
      int ch_ = (kk_ * 4 + lk) ^ (lr & 7);                                   \
      bq[n_][kk_] = *reinterpret_cast<const bf16x8*>(                        \
          lds + 32768 + (p) * 16384 + row_ * 64 + ch_ * 8);                  \
    }

#define LDA_Q(p, q)                                                          \
  _Pragma("unroll")                                                          \
  for (int i_ = 0; i_ < 2; ++i_)                                             \
    _Pragma("unroll")                                                        \
    for (int kk_ = 0; kk_ < 2; ++kk_) {                                      \
      int row_ = wr * 128 + ((q) * 2 + i_) * 16 + lr;                        \
      int ch_ = (kk_ * 4 + lk) ^ (lr & 7);                                   \
      af[i_][kk_] = *reinterpret_cast<const bf16x8*>(                        \
          lds + (p) * 16384 + row_ * 64 + ch_ * 8);                          \
    }

#define MFMA_Q(q)                                                            \
  __builtin_amdgcn_s_setprio(1);                                             \
  _Pragma("unroll")                                                          \
  for (int i_ = 0; i_ < 2; ++i_)                                             \
    _Pragma("unroll")                                                        \
    for (int n_ = 0; n_ < 4; ++n_)                                           \
      _Pragma("unroll")                                                      \
      for (int kk_ = 0; kk_ < 2; ++kk_)                                      \
        acc[(q) * 2 + i_][n_] = __builtin_amdgcn_mfma_f32_16x16x32_bf16(     \
            af[i_][kk_], bq[n_][kk_], acc[(q) * 2 + i_][n_], 0, 0, 0);       \
  __builtin_amdgcn_s_setprio(0);

  STAGE_HALF(A, abase, 0, 0, 0);
  STAGE_HALF(A, abase, 0, 1, 0);
  STAGE_HALF(Bt, bbase, 0, 0, 32768);
  STAGE_HALF(Bt, bbase, 0, 1, 32768);
  STAGE_HALF(Bt, bbase, 1, 0, 49152);
  STAGE_HALF(Bt, bbase, 1, 1, 49152);
  VMCNT(4);
  BAR();

  const int niter = nt >> 1;
  for (int tp = 0; tp < niter; ++tp) {
    const int T = tp << 1;
    const bool more = (T + 2 < nt);
    bf16x8 af[2][2], bq[4][2];

    // ---- tile T (parity 0) ----
    LDB_ALL(0); LDA_Q(0, 0);
    STAGE_HALF(A, abase, T + 1, 0, 16384);
    BAR(); LGKM0(); MFMA_Q(0); BAR();
    LDA_Q(0, 1);
    STAGE_HALF(A, abase, T + 1, 1, 16384);
    BAR(); LGKM0(); MFMA_Q(1); BAR();
    LDA_Q(0, 2);
    if (more) STAGE_HALF(Bt, bbase, T + 2, 0, 32768);
    BAR(); LGKM0(); MFMA_Q(2); BAR();
    LDA_Q(0, 3);
    if (more) { STAGE_HALF(Bt, bbase, T + 2, 1, 32768); VMCNT(4); }
    else VMCNT(0);
    BAR(); LGKM0(); MFMA_Q(3); BAR();

    // ---- tile T+1 (parity 1) ----
    LDB_ALL(1); LDA_Q(1, 0);
    if (more) STAGE_HALF(A, abase, T + 2, 0, 0);
    BAR(); LGKM0(); MFMA_Q(0); BAR();
    LDA_Q(1, 1);
    if (more) STAGE_HALF(A, abase, T + 2, 1, 0);
    BAR(); LGKM0(); MFMA_Q(1); BAR();
    LDA_Q(1, 2);
    if (more) STAGE_HALF(Bt, bbase, T + 3, 0, 49152);
    BAR(); LGKM0(); MFMA_Q(2); BAR();
    LDA_Q(1, 3);
    if (more) { STAGE_HALF(Bt, bbase, T + 3, 1, 49152); VMCNT(4); }
    BAR(); LGKM0(); MFMA_Q(3); BAR();
  }

  const long mrow = m0 + wr * 128;
  const long ncol = n0 + wc * 64;
#pragma unroll
  for (int n = 0; n < 4; ++n) {
    long col = ncol + n * 16 + lr;
    float bb = bias[col];
    if (OUT_BF16) {
#pragma unroll
      for (int m = 0; m < 8; ++m)
#pragma unroll
        for (int j = 0; j < 4; ++j) {
          long row = mrow + m * 16 + lk * 4 + j;
          unsigned h = f2bf(acc[m][n][j] + bb);
          unsigned ph = h | (((unsigned)__shfl_xor((int)h, 1, 64)) << 16);
          unsigned p2 = (unsigned)__shfl_xor((int)ph, 2, 64);
          if ((lane & 3) == 0) {
            uint2 o; o.x = ph; o.y = p2;
            *reinterpret_cast<uint2*>((u16*)Cv + row * N + col) = o;
          }
        }
    } else {
#pragma unroll
      for (int m = 0; m < 8; ++m)
#pragma unroll
        for (int j = 0; j < 4; ++j) {
          long row = mrow + m * 16 + lk * 4 + j;
          ((float*)Cv)[row * N + col] = acc[m][n][j] + bb;
        }
    }
  }
#undef STAGE_HALF
#undef LDB_ALL
#undef LDA_Q
#undef MFMA_Q
}

// ---------------- fused attention: 16 q-rows per block, in-place on Q ------
// Q [16*4096][1024] bf16 (overwritten), Kp [16][80][1024] bf16,
// Vt [16][1024][96] bf16 (V transposed, k-pad zeroed).
__global__ __launch_bounds__(256) void attn_fused(u16* __restrict__ Q,
                                                  const u16* __restrict__ Kp,
                                                  const u16* __restrict__ Vt) {
  const int blk = blockIdx.x;
  const int b = blk >> 8;               // 256 blocks per batch (4096/16)
  const int q0 = (blk & 255) << 4;
  const long qoff = ((long)b * 4096 + q0) * 1024;
  const int tid = threadIdx.x;
  const int lane = tid & 63, wave = tid >> 6;
  const int lr = lane & 15, lk = lane >> 4;

  __shared__ float S4[4][16][80];
  __shared__ __align__(16) u16 P_lds[16][104];  // bf16 P, stride 104 breaks banks

  // Phase 1: scores via MFMA; wave w covers k-dim slice w*256 .. +255
  f32x4 acc[5] = {};
  const u16* qb = Q + qoff;
  const u16* kb = Kp + (long)b * 80 * 1024;
#pragma unroll
  for (int t = 0; t < 8; ++t) {
    int kk = wave * 8 + t;
    bf16x8 qa = *reinterpret_cast<const bf16x8*>(qb + lr * 1024 + kk * 32 + lk * 8);
#pragma unroll
    for (int n = 0; n < 5; ++n) {
      bf16x8 kf = *reinterpret_cast<const bf16x8*>(kb + (n * 16 + lr) * 1024 + kk * 32 + lk * 8);
      acc[n] = __builtin_amdgcn_mfma_f32_16x16x32_bf16(qa, kf, acc[n], 0, 0, 0);
    }
  }
#pragma unroll
  for (int n = 0; n < 5; ++n)
#pragma unroll
    for (int j = 0; j < 4; ++j)
      S4[wave][lk * 4 + j][n * 16 + lr] = acc[n][j];
  __syncthreads();

  // Phase 2: cross-wave reduce + softmax -> P_lds (bf16, cols 80..95 zeroed)
  {
    const int r = tid >> 4, ci = tid & 15;
    const float scale = 0.088388347648318447f;  // 1/sqrt(128)
    float v[5];
    float mx = -3e38f;
#pragma unroll
    for (int i = 0; i < 5; ++i) {
      int c = ci + 16 * i;
      float s = (S4[0][r][c] + S4[1][r][c]) + (S4[2][r][c] + S4[3][r][c]);
      s *= scale;
      if (c >= 77) s = -3e38f;
      v[i] = s;
      mx = fmaxf(mx, s);
    }
#pragma unroll
    for (int off = 1; off < 16; off <<= 1) mx = fmaxf(mx, __shfl_xor(mx, off, 64));
    float sum = 0.f, e[5];
#pragma unroll
    for (int i = 0; i < 5; ++i) { e[i] = __expf(v[i] - mx); sum += e[i]; }
#pragma unroll
    for (int off = 1; off < 16; off <<= 1) sum += __shfl_xor(sum, off, 64);
    float inv = 1.f / sum;
#pragma unroll
    for (int i = 0; i < 5; ++i) P_lds[r][ci + 16 * i] = f2bf(e[i] * inv);
    P_lds[r][80 + ci] = 0;
  }
  __syncthreads();

  // Phase 3: PV via MFMA. A = P (rows = q), B = Vt rows (cols = e), K = 96.
  bf16x8 pa[3];
#pragma unroll
  for (int kk = 0; kk < 3; ++kk)
    pa[kk] = *reinterpret_cast<const bf16x8*>(&P_lds[lr][kk * 32 + lk * 8]);
  const u16* vt = Vt + (long)b * 1024 * 96;
  u16* ob = Q + qoff;
#pragma unroll
  for (int n = 0; n < 16; ++n) {
    int col = wave * 256 + n * 16 + lr;
    f32x4 o = {};
#pragma unroll
    for (int kk = 0; kk < 3; ++kk) {
      bf16x8 vq = *reinterpret_cast<const bf16x8*>(vt + (long)col * 96 + kk * 32 + lk * 8);
      o = __builtin_amdgcn_mfma_f32_16x16x32_bf16(pa[kk], vq, o, 0, 0, 0);
    }
#pragma unroll
    for (int j = 0; j < 4; ++j) {
      unsigned h = f2bf(o[j]);
      unsigned ph = h | (((unsigned)__shfl_xor((int)h, 1, 64)) << 16);
      unsigned p2 = (unsigned)__shfl_xor((int)ph, 2, 64);
      if ((lane & 3) == 0) {
        uint2 st; st.x = ph; st.y = p2;
        *reinterpret_cast<uint2*>(ob + (long)(lk * 4 + j) * 1024 + col) = st;
      }
    }
  }
}

extern "C" void kernel_launch(void* const* d_in, const int* in_sizes, int n_in,
                              void* d_out, int out_size, void* d_ws, size_t ws_size,
                              hipStream_t stream) {
  const float* x  = (const float*)d_in[0];
  const float* y  = (const float*)d_in[1];
  const float* Wq = (const float*)d_in[2];
  const float* bq = (const float*)d_in[3];
  const float* Wk = (const float*)d_in[4];
  const float* bk = (const float*)d_in[5];
  const float* Wv = (const float*)d_in[6];
  const float* bv = (const float*)d_in[7];
  const float* Wo = (const float*)d_in[8];
  const float* bo = (const float*)d_in[9];

  const int B = 16, Lq = 4096, D = 1024, Dc = 768, Lp = 80;
  const long Mq = (long)B * Lq;  // 65536

  char* p = (char*)d_ws;
  u16* Qb  = (u16*)p; p += (size_t)Mq * D * 2;      // Q, then attn out (in-place)
  u16* Wqt = (u16*)p; p += (size_t)D * D * 2;
  u16* Wkt = (u16*)p; p += (size_t)D * Dc * 2;      // [1024][768]
  u16* Wvt = (u16*)p; p += (size_t)D * Dc * 2;
  u16* Wot = (u16*)p; p += (size_t)D * D * 2;
  u16* yp  = (u16*)p; p += (size_t)B * Lp * Dc * 2; // [16][80][768], pad zeroed
  u16* Kp  = (u16*)p; p += (size_t)B * Lp * D * 2;  // [16][80][1024]
  u16* Vp  = (u16*)p; p += (size_t)B * Lp * D * 2;
  u16* Vt  = (u16*)p; p += (size_t)B * D * 96 * 2;  // [16][1024][96]
  u16* xb  = (u16*)d_out;  // scratch: x as bf16 lives in d_out until final GEMM

  (void)hipFuncSetAttribute(reinterpret_cast<const void*>(&gemm8<true>),
                            hipFuncAttributeMaxDynamicSharedMemorySize, 131072);
  (void)hipFuncSetAttribute(reinterpret_cast<const void*>(&gemm8<false>),
                            hipFuncAttributeMaxDynamicSharedMemorySize, 131072);

  // conversions
  cvt_f32_bf16<<<(int)(Mq * D / 1024), 256, 0, stream>>>(x, xb, Mq * D / 4);
  transpose_cvt<<<dim3(D / 32, D / 32), 256, 0, stream>>>(Wq, Wqt, D, D);
  transpose_cvt<<<dim3(D / 32, Dc / 32), 256, 0, stream>>>(Wk, Wkt, Dc, D);
  transpose_cvt<<<dim3(D / 32, Dc / 32), 256, 0, stream>>>(Wv, Wvt, Dc, D);
  transpose_cvt<<<dim3(D / 32, D / 32), 256, 0, stream>>>(Wo, Wot, D, D);
  cvt_y_pad<<<(B * Lp * Dc / 4) / 256, 256, 0, stream>>>(y, yp);

  // K/V projections: [1280][768] @ [768][1024] -> [1280][1024]
  gemm8<true><<<(1280 / 256) * (D / 256), 512, 131072, stream>>>(yp, Wkt, bk, Kp, B * Lp, D, Dc);
  gemm8<true><<<(1280 / 256) * (D / 256), 512, 131072, stream>>>(yp, Wvt, bv, Vp, B * Lp, D, Dc);

  // V transpose for MFMA PV: [16][80][1024] -> [16][1024][96]
  transpose_v<<<dim3(D / 32, 3, B), 256, 0, stream>>>(Vp, Vt);

  // Q projection: [65536][1024] @ [1024][1024] -> [65536][1024] bf16
  gemm8<true><<<(int)(Mq / 256) * (D / 256), 512, 131072, stream>>>(xb, Wqt, bq, Qb, (int)Mq, D, D);

  // fused attention, writes back into Qb
  attn_fused<<<(int)(Mq / 16), 256, 0, stream>>>(Qb, Kp, Vt);

  // output projection: [65536][1024] @ [1024][1024] -> d_out f32
  gemm8<false><<<(int)(Mq / 256) * (D / 256), 512, 131072, stream>>>(Qb, Wot, bo, d_out, (int)Mq, D, D);
}